// Round 13
// baseline (173.815 us; speedup 1.0000x reference)
//
#include <hip/hip_runtime.h>
#include <math.h>

// SoftRasterizer: B=1, V=5023, F=10000, IMG=128.
// R13 = R12 (139us, k_main 77) with per-WAVE 8x8 pixel regions:
//  - k_bin (tile x quarter) emits 4 region sublists (region-level tight test,
//    strictly tighter than tile-level) storing fid only; z-desc order kept.
//  - k_map assigns W=4B wave-slots proportionally to region list lengths.
//  - k_main: 4 independent waves per block (no syncthreads), each walks its
//    region's 4 quarter-lists; wave-level absorbing break.
//  - k_reduce: one block per region, 4 subs x 64 px, guarded exact merge.
// Eval arithmetic bit-identical to R6-R12 (absmax 0.0078 <= 0.02).
//
// fb2 record layout (40 floats), z-desc order:
//  0-3  bxmin bxmax bymin bymax | 4-7 x2 y2 a0 b0 | 8-11 a1 b1 detp zub(bucket)
// 12-15 m0 m1 m2 mult | 16-19 x0 y0 x1 y1 | 20-23 il01 il12 il20 rdetp
// 24-29 rz0 rz1 rz2 rg0 rg1 rg2 | 30-38 tex[9] | 39 pad

#define NFACE 10000
#define IMG   128
#define P_TOT (IMG*IMG)
#define FSTR  40
#define NREG  256              // 16x16 regions of 8x8 px
#define NQ    4
#define CAPQ  2500             // quarter size (hard bound)
#define WMAX  16384            // max wave slots
#define NB    1024             // z buckets
#define CH    256
#define NCH   40               // NFACE/CH
#define Z_LO  0.85f
#define Z_W   (0.12f/1024.0f)

__device__ __forceinline__ float rcp_nr(float x) {
    float r = __builtin_amdgcn_rcpf(x);
    r = r * __builtin_fmaf(-x, r, 2.0f);
    return r;
}

__device__ __forceinline__ float segd(float px, float py, float ax, float ay,
                                      float bx, float by, float il) {
    float dx = px - ax, dy = py - ay;
    float ex = bx - ax, ey = by - ay;
    float t = (dx * ex + dy * ey) * il;
    t = fminf(fmaxf(t, 0.0f), 1.0f);
    float rx = dx - t * ex, ry = dy - t * ey;
    return rx * rx + ry * ry;
}

__device__ __forceinline__ int zbucket(float zub) {
    int b = (int)((zub - Z_LO) * (1.0f / Z_W));
    return min(max(b, 0), NB - 1);
}

// fused k_pre + k_hist
__global__ __launch_bounds__(256) void k_prehist(const float* __restrict__ v,
                                                 const int* __restrict__ fc,
                                                 const float* __restrict__ at,
                                                 float* __restrict__ fb,
                                                 int* __restrict__ hist) {
    __shared__ int lh[NB];
    int c = blockIdx.x, tid = threadIdx.x;
    for (int j = tid; j < NB; j += 256) lh[j] = 0;
    __syncthreads();

    int f = c * CH + tid;
    if (f < NFACE) {
        int i0 = fc[3 * f], i1 = fc[3 * f + 1], i2 = fc[3 * f + 2];
        float x0 = -v[3 * i0], y0 = v[3 * i0 + 1], z0 = v[3 * i0 + 2];
        float x1 = -v[3 * i1], y1 = v[3 * i1 + 1], z1 = v[3 * i1 + 2];
        float x2 = -v[3 * i2], y2 = v[3 * i2 + 1], z2 = v[3 * i2 + 2];

        float det = (y1 - y2) * (x0 - x2) + (x2 - x1) * (y0 - y2);
        if (fabsf(det) < 1e-10f) det = (det < 0.0f) ? -1e-10f : 1e-10f;
        float a0 = y1 - y2, b0 = x2 - x1, a1 = y2 - y0, b1 = x0 - x2, detp = det;
        if (det < 0.0f) { detp = -det; a0 = -a0; b0 = -b0; a1 = -a1; b1 = -b1; }

        float a2 = a0 + a1, b2 = b0 + b1;
        float g0 = fmaxf(sqrtf(a0 * a0 + b0 * b0), 1e-12f);
        float g1 = fmaxf(sqrtf(a1 * a1 + b1 * b1), 1e-12f);
        float g2 = fmaxf(sqrtf(a2 * a2 + b2 * b2), 1e-12f);
        const float MARG = 3e-5f, AG = 1e-9f;
        float m0 = -(MARG * g0 + AG), m1 = -(MARG * g1 + AG), m2 = -(MARG * g2 + AG);

        float e01x = x1 - x0, e01y = y1 - y0;
        float e12x = x2 - x1, e12y = y2 - y1;
        float e20x = x0 - x2, e20y = y0 - y2;
        float il01 = 1.0f / fmaxf(e01x * e01x + e01y * e01y, 1e-12f);
        float il12 = 1.0f / fmaxf(e12x * e12x + e12y * e12y, 1e-12f);
        float il20 = 1.0f / fmaxf(e20x * e20x + e20y * e20y, 1e-12f);

        const float BM = 2e-5f;
        float bxmin = fminf(fminf(x0, x1), x2) - BM, bxmax = fmaxf(fmaxf(x0, x1), x2) + BM;
        float bymin = fminf(fminf(y0, y1), y2) - BM, bymax = fmaxf(fmaxf(y0, y1), y2) + BM;

        int mult = (((y2 - y0) * (x1 - x0)) < ((y1 - y0) * (x2 - x0)))
                 + (((y0 - y2) * (x1 - x2)) < ((y1 - y2) * (x0 - x2)));

        float zmin = fminf(fminf(z0, z1), z2);
        float zub = (100.0f - zmin) / 99.0f + 2e-6f;

        float* F = fb + (size_t)f * FSTR;
        F[0] = bxmin; F[1] = bxmax; F[2] = bymin; F[3] = bymax;
        F[4] = x2; F[5] = y2; F[6] = a0; F[7] = b0;
        F[8] = a1; F[9] = b1; F[10] = detp; F[11] = zub;
        F[12] = m0; F[13] = m1; F[14] = m2; F[15] = (float)mult;
        F[16] = x0; F[17] = y0; F[18] = x1; F[19] = y1;
        F[20] = il01; F[21] = il12; F[22] = il20; F[23] = 1.0f / detp;
        F[24] = 1.0f / z0; F[25] = 1.0f / z1; F[26] = 1.0f / z2;
        F[27] = 1.0f / g0; F[28] = 1.0f / g1; F[29] = 1.0f / g2;
#pragma unroll
        for (int k = 0; k < 9; k++) F[30 + k] = at[(size_t)f * 9 + k];
        F[39] = 0.0f;

        atomicAdd(&lh[zbucket(zub)], 1);
    }
    __syncthreads();
    for (int j = tid; j < NB; j += 256) hist[c * NB + j] = lh[j];
}

// one block: suffix-sum over buckets (desc) + per-chunk bases; zero len[]
__global__ __launch_bounds__(1024) void k_scan(int* __restrict__ hist,
                                               int* __restrict__ len) {
    __shared__ int a[NB];
    int t = threadIdx.x;
    if (t < NREG) len[t] = 0;
    int tot = 0;
    for (int c = 0; c < NCH; c++) tot += hist[c * NB + t];
    a[t] = tot;
    for (int off = 1; off < NB; off <<= 1) {
        __syncthreads();
        int v = a[t] + ((t + off < NB) ? a[t + off] : 0);
        __syncthreads();
        a[t] = v;
    }
    int r = a[t] - tot;
    for (int c = 0; c < NCH; c++) {
        int h = hist[c * NB + t];
        hist[c * NB + t] = r;
        r += h;
    }
}

// scatter + physical reorder: fb2[pos] = fb[f], F[11] := bucket upper bound
__global__ __launch_bounds__(256) void k_scatterre(const float* __restrict__ fb,
                                                   const int* __restrict__ hist,
                                                   float* __restrict__ fb2) {
    __shared__ int sb[CH];
    int c = blockIdx.x, tid = threadIdx.x;
    int f = c * CH + tid;
    bool valid = (f < NFACE);
    int b = valid ? zbucket(fb[(size_t)f * FSTR + 11]) : -1;
    sb[tid] = b;
    __syncthreads();
    if (valid) {
        int rank = 0;
        for (int j = 0; j < CH; j++) {
            int v2 = sb[j];
            rank += (j < tid && v2 == b) ? 1 : 0;
        }
        int pos = hist[c * NB + b] + rank;
        const float4* src = (const float4*)(fb + (size_t)f * FSTR);
        float4* dst = (float4*)(fb2 + (size_t)pos * FSTR);
#pragma unroll
        for (int k = 0; k < 10; k++) dst[k] = src[k];
        fb2[(size_t)pos * FSTR + 11] = Z_LO + (float)(b + 1) * Z_W + 1e-7f;
    }
}

// 256 blocks: (tile, quarter). Emits 4 region sublists (8x8 px regions) with
// region-level tight test. Lists store fid only; z-desc order preserved.
__global__ __launch_bounds__(256) void k_bin(const float* __restrict__ fb2,
                                             int* __restrict__ rlist,
                                             int* __restrict__ cnt16,
                                             int* __restrict__ len) {
    int t = blockIdx.x >> 2, q = blockIdx.x & 3;
    int tid = threadIdx.x, wv = tid >> 6, lane = tid & 63;
    int tx = t & 7, ty = t >> 3;

    // region NDC geometry for the 4 sub-regions (sx,sy in {0,1})
    float rxlo[4], rxhi[4], rylo[4], ryhi[4], rcx[4], rcy[4], rhx[4], rhy[4];
    int rgl[4];
#pragma unroll
    for (int rl = 0; rl < 4; rl++) {
        int sx = rl & 1, sy = rl >> 1;
        int rx = tx * 2 + sx, ry = ty * 2 + sy;
        rgl[rl] = ry * 16 + rx;
        float xl = (float)(2 * (rx * 8) + 1 - IMG) / (float)IMG;
        float xh = (float)(2 * (rx * 8 + 7) + 1 - IMG) / (float)IMG;
        float yh = (float)(127 - 2 * (ry * 8)) / (float)IMG;
        float yl = (float)(127 - 2 * (ry * 8 + 7)) / (float)IMG;
        rxlo[rl] = xl; rxhi[rl] = xh; rylo[rl] = yl; ryhi[rl] = yh;
        rcx[rl] = 0.5f * (xl + xh); rhx[rl] = 0.5f * (xh - xl);
        rcy[rl] = 0.5f * (yl + yh); rhy[rl] = 0.5f * (yh - yl);
    }
    // tile bounds for quick reject
    float tx_lo = rxlo[0], tx_hi = rxhi[1];
    float ty_lo = rylo[2], ty_hi = ryhi[0];

    __shared__ int wc[4];
    int cnt[4] = {0, 0, 0, 0};
    int f0 = q * CAPQ;
    for (int base = f0; base < f0 + CAPQ; base += 256) {
        int j = base + tid;
        bool ov[4] = {false, false, false, false};
        {
            const float4* H = (const float4*)(fb2 + (size_t)j * FSTR);
            float4 h0 = H[0], h1 = H[1], h2 = H[2], h3 = H[3];
            bool tov = (h0.x <= tx_hi) & (h0.y >= tx_lo) & (h0.z <= ty_hi) & (h0.w >= ty_lo);
            if (tov) {
                float A2 = -(h1.z + h2.x), B2 = -(h1.w + h2.y);
#pragma unroll
                for (int rl = 0; rl < 4; rl++) {
                    bool o = (h0.x <= rxhi[rl]) & (h0.y >= rxlo[rl]) &
                             (h0.z <= ryhi[rl]) & (h0.w >= rylo[rl]);
                    if (o) {
                        float dx = rcx[rl] - h1.x, dy = rcy[rl] - h1.y;
                        float hx = rhx[rl], hy = rhy[rl];
                        float mx0 = h1.z * dx + h1.w * dy + fabsf(h1.z) * hx + fabsf(h1.w) * hy;
                        float mx1 = h2.x * dx + h2.y * dy + fabsf(h2.x) * hx + fabsf(h2.y) * hy;
                        float mx2 = h2.z + A2 * dx + B2 * dy + fabsf(A2) * hx + fabsf(B2) * hy;
                        o = (mx0 >= h3.x) & (mx1 >= h3.y) & (mx2 >= h3.z);
                    }
                    ov[rl] = o;
                }
            }
        }
#pragma unroll
        for (int rl = 0; rl < 4; rl++) {
            unsigned long long mask = __ballot(ov[rl]);
            if (lane == 0) wc[wv] = __popcll(mask);
            __syncthreads();
            int off = cnt[rl];
            for (int w = 0; w < 4; ++w) {
                if (w < wv) off += wc[w];
            }
            if (ov[rl]) {
                int pos = off + __popcll(mask & ((1ull << lane) - 1ull));
                rlist[((size_t)rgl[rl] * 4 + q) * CAPQ + pos] = j;
            }
            cnt[rl] += wc[0] + wc[1] + wc[2] + wc[3];
            __syncthreads();
        }
    }
    if (tid == 0) {
#pragma unroll
        for (int rl = 0; rl < 4; rl++) {
            cnt16[rgl[rl] * 4 + q] = cnt[rl];
            atomicAdd(&len[rgl[rl]], cnt[rl]);
        }
    }
}

// one block, 256 threads: wave-slot map. S_r ~ len_r, sum <= W.
__global__ __launch_bounds__(256) void k_map(const int* __restrict__ len,
                                             int* __restrict__ map,
                                             int* __restrict__ starts,
                                             int* __restrict__ Sarr,
                                             int W) {
    __shared__ int sL[NREG], sS[NREG], sP[NREG], sTot;
    int rr = threadIdx.x;
    sL[rr] = len[rr];
    __syncthreads();
    if (rr == 0) {
        int tot = 0;
        for (int k = 0; k < NREG; k++) tot += sL[k];
        sTot = max(tot, 1);
    }
    __syncthreads();
    int tot = sTot;
    int S = max(1, (int)(((long long)sL[rr] * (long long)(W - NREG)) /
                         (long long)tot));
    sS[rr] = S;
    __syncthreads();
    if (rr == 0) {
        int acc = 0;
        for (int k = 0; k < NREG; k++) { sP[k] = acc; acc += sS[k]; }
    }
    __syncthreads();
    starts[rr] = sP[rr];
    Sarr[rr] = sS[rr];
    int used = sP[NREG - 1] + sS[NREG - 1];
    for (int i = rr; i < W; i += 256) {
        int mv = -1;
        if (i < used) {
            int lo = 0, hi = NREG - 1;          // largest k with sP[k] <= i
            while (lo < hi) {
                int mid = (lo + hi + 1) >> 1;
                if (sP[mid] <= i) lo = mid; else hi = mid - 1;
            }
            mv = (lo << 16) | (i - sP[lo]);
        }
        map[i] = mv;
    }
}

// B blocks x 4 independent waves; wave = one slot = one 8x8 region segment
__global__ __launch_bounds__(256) void k_main(const float* __restrict__ fb2,
                                              const int* __restrict__ rlist,
                                              const int* __restrict__ cnt16,
                                              const int* __restrict__ map,
                                              const int* __restrict__ Sarr,
                                              float* __restrict__ part) {
    int slot = blockIdx.x * 4 + (threadIdx.x >> 6);
    int lane = threadIdx.x & 63;
    int mv = map[slot];
    if (mv < 0) return;
    int r = mv >> 16, seg = mv & 0xffff;
    int Sr = Sarr[r];
    int rx = r & 15, ry = r >> 4;
    int col = rx * 8 + (lane & 7);
    int row = ry * 8 + (lane >> 3);
    float px = (float)(2 * col + 1 - IMG) / (float)IMG;
    float py = (float)(2 * (IMG - 1 - row) + 1 - IMG) / (float)IMG;

    float m = -__builtin_inff();
    float s = 0.0f, ca = 0.0f, cb = 0.0f, cc = 0.0f, pr = 1.0f;

    const float NEAR_T = 4.3e-3f;   // lb > this => sigmoid rounds to 1.0f exactly
    const float ZM = 1.3e-4f;       // exp((zpn-m)*1e6) == 0.0f beyond this gap

    bool done = false;
    for (int q = 0; q < 4 && !done; ++q) {
        int qlen = cnt16[r * 4 + q];
        const int* lst = rlist + ((size_t)r * 4 + q) * CAPQ;
        for (int i = seg; i < qlen; i += Sr) {
            int fj = __builtin_amdgcn_readfirstlane(lst[i]);
            const float4* H = (const float4*)(fb2 + (size_t)fj * FSTR);
            float4 g0 = H[0], g1 = H[1], g2 = H[2], g3 = H[3];
            float zcur = g2.w;
            // absorbing state: list is zub-desc globally => rest is no-op
            if (__all((pr == 0.0f) & (zcur <= m - ZM))) { done = true; break; }

            bool inbox = (px >= g0.x) & (px <= g0.y) & (py >= g0.z) & (py <= g0.w);
            if (!__any(inbox)) continue;

            float x2 = g1.x, y2 = g1.y;
            float dx2 = px - x2, dy2 = py - y2;
            float num0 = g1.z * dx2 + g1.w * dy2;
            float num1 = g2.x * dx2 + g2.y * dy2;
            float detp = g2.z;
            float num2 = detp - num0 - num1;
            bool maybe = inbox & (num0 >= g3.x) & (num1 >= g3.y) & (num2 >= g3.z);
            if (!__any(maybe)) continue;

            const float* F = fb2 + (size_t)fj * FSTR;

            bool inside = (num0 >= 0.0f) & (num1 >= 0.0f) & (num2 >= 0.0f);
            bool inside_l = inside & inbox;

            float lin0 = num0 * F[27];
            float lin1 = num1 * F[28];
            float lin2 = num2 * F[29];
            float lbmin = fminf(fminf(lin0, lin1), lin2);

            bool outNear = maybe & (!inside);
            bool nearIn  = inside_l & (lbmin < NEAR_T);
            bool anyNear = __any(nearIn | outNear);

            float dis = 1e9f;
            float Dp;
            if (anyNear) {
                bool needAll = __any(outNear);
                float x0 = F[16], y0 = F[17], x1 = F[18], y1 = F[19];
                float d01 = 1e9f, d12 = 1e9f, d20 = 1e9f;
                if (needAll | __any(inside_l & (lin2 < NEAR_T)))
                    d01 = segd(px, py, x0, y0, x1, y1, F[20]);
                if (needAll | __any(inside_l & (lin0 < NEAR_T)))
                    d12 = segd(px, py, x1, y1, x2, y2, F[21]);
                if (needAll | __any(inside_l & (lin1 < NEAR_T)))
                    d20 = segd(px, py, x2, y2, x0, y0, F[22]);
                dis = fminf(fminf(d01, d12), d20);

                float qq = dis * 1e6f;
                float xs_ = inside ? qq : -qq;
                float tt = __expf(-fabsf(xs_));
                float Dpn = (xs_ >= 0.0f ? 1.0f : tt) * rcp_nr(1.0f + tt);
                bool nearl = nearIn | outNear;
                Dp = nearl ? Dpn : (inside_l ? 1.0f : 0.0f);
            } else {
                Dp = inside_l ? 1.0f : 0.0f;
            }

            bool contrib = inside_l | (outNear & (dis < 1e-10f));
            Dp = contrib ? Dp : 0.0f;
            float omd = 1.0f - Dp;
            pr *= contrib ? (omd * omd) : 1.0f;   // both winding copies

            float multf = g3.w;
            bool doz = contrib & (multf > 0.0f);
            if (__any(doz & (zcur > m - ZM))) {
                float rdetp = F[23];
                float w0 = num0 * rdetp;
                float w1 = num1 * rdetp;
                float c0 = fminf(fmaxf(w0, 0.0f), 1.0f);
                float c1 = fminf(fmaxf(w1, 0.0f), 1.0f);
                float c2 = fminf(fmaxf(1.0f - w0 - w1, 0.0f), 1.0f);
                float csum = fmaxf(c0 + c1 + c2, 1e-5f);
                float rcs = rcp_nr(csum);
                c0 *= rcs; c1 *= rcs; c2 *= rcs;
                float zpi = c0 * F[24] + c1 * F[25] + c2 * F[26];
                if (fabsf(zpi) < 1e-12f) zpi = 1e-12f;
                float zp = rcp_nr(zpi);
                if (doz & (zp >= 1.0f) & (zp <= 100.0f)) {
                    float zpn = (100.0f - zp) / 99.0f;   // keep IEEE: critical
                    if (zpn > m) {
                        float scl = __expf((m - zpn) * 1e6f);
                        s *= scl; ca *= scl; cb *= scl; cc *= scl;
                        m = zpn;
                    }
                    float arg = (zpn - m) * 1e6f;
                    if (arg > -110.0f) {
                        float e = __expf(arg) * Dp * multf;
                        float col0 = c0 * F[30] + c1 * F[33] + c2 * F[36];
                        float col1 = c0 * F[31] + c1 * F[34] + c2 * F[37];
                        float col2 = c0 * F[32] + c1 * F[35] + c2 * F[38];
                        s += e; ca += e * col0; cb += e * col1; cc += e * col2;
                    }
                }
            }
        }
    }

    size_t pb = (size_t)slot * 6 * 64;
    part[pb + 0 * 64 + lane] = m;
    part[pb + 1 * 64 + lane] = s;
    part[pb + 2 * 64 + lane] = ca;
    part[pb + 3 * 64 + lane] = cb;
    part[pb + 4 * 64 + lane] = cc;
    part[pb + 5 * 64 + lane] = pr;
}

// one block per region: 4 subs x 64 px; guarded exact online-softmax merge
__global__ __launch_bounds__(256) void k_reduce(const float* __restrict__ part,
                                                const int* __restrict__ starts,
                                                const int* __restrict__ Sarr,
                                                float* __restrict__ out) {
    __shared__ float sm[4][64], ss[4][64], sa[4][64], sb2[4][64],
                     sc[4][64], sp[4][64];
    int r = blockIdx.x;
    int tid = threadIdx.x;
    int lane = tid & 63, sub = tid >> 6;
    int start = starts[r], S = Sarr[r];

    const float NINF = -__builtin_inff();
    float mp = NINF;
    for (int sgi = sub; sgi < S; sgi += 4)
        mp = fmaxf(mp, part[((size_t)(start + sgi) * 6 + 0) * 64 + lane]);
    float sum = 0.0f, a = 0.0f, b = 0.0f, c = 0.0f, pr = 1.0f;
    for (int sgi = sub; sgi < S; sgi += 4) {
        const float* rp = part + ((size_t)(start + sgi) * 6) * 64;
        float rm = rp[0 * 64 + lane];
        float w = (rm == NINF) ? 0.0f : __expf((rm - mp) * 1e6f);
        pr *= rp[5 * 64 + lane];
        if (__any(w != 0.0f)) {
            sum += rp[1 * 64 + lane] * w;
            a += rp[2 * 64 + lane] * w;
            b += rp[3 * 64 + lane] * w;
            c += rp[4 * 64 + lane] * w;
        }
    }
    sm[sub][lane] = mp; ss[sub][lane] = sum; sa[sub][lane] = a;
    sb2[sub][lane] = b; sc[sub][lane] = c;  sp[sub][lane] = pr;
    __syncthreads();
    if (sub == 0) {
        int rx = r & 15, ry = r >> 4;
        int col = rx * 8 + (lane & 7);
        int row = ry * 8 + (lane >> 3);
        int p = row * IMG + col;
        float M = 0.001f;   // BG_EPS
#pragma unroll
        for (int k = 0; k < 4; k++) M = fmaxf(M, sm[k][lane]);
        float SUM = __expf((0.001f - M) * 1e6f);   // background (s0=1); M finite
        float A = 0.0f, B2 = 0.0f, C = 0.0f, PR = 1.0f;
#pragma unroll
        for (int k = 0; k < 4; k++) {
            float w = __expf((sm[k][lane] - M) * 1e6f);   // sm=-inf -> 0
            SUM += ss[k][lane] * w;
            A += sa[k][lane] * w;
            B2 += sb2[k][lane] * w;
            C += sc[k][lane] * w;
            PR *= sp[k][lane];
        }
        out[0 * P_TOT + p] = A / SUM;
        out[1 * P_TOT + p] = B2 / SUM;
        out[2 * P_TOT + p] = C / SUM;
        out[3 * P_TOT + p] = 1.0f - PR;
    }
}

extern "C" void kernel_launch(void* const* d_in, const int* in_sizes, int n_in,
                              void* d_out, int out_size, void* d_ws, size_t ws_size,
                              hipStream_t stream) {
    const float* verts = (const float*)d_in[0];
    const int*   faces = (const int*)d_in[1];
    const float* attrs = (const float*)d_in[2];
    float* out = (float*)d_out;
    float* ws  = (float*)d_ws;

    float* fb     = ws;                                      // 400k floats
    int*   hist   = (int*)(fb + (size_t)NFACE * FSTR);       // NCH*NB
    float* fb2    = (float*)(hist + NCH * NB);               // 400k floats
    int*   rlist  = (int*)(fb2 + (size_t)NFACE * FSTR);      // NREG*4*CAPQ
    int*   cnt16  = rlist + (size_t)NREG * 4 * CAPQ;         // 1024
    int*   len    = cnt16 + NREG * 4;                        // 256
    int*   map    = len + NREG;                              // WMAX
    int*   starts = map + WMAX;                              // 256
    int*   Sarr   = starts + NREG;                           // 256
    float* part   = (float*)(Sarr + NREG);

    size_t used_f = 2 * (size_t)NFACE * FSTR + NCH * NB
                  + (size_t)NREG * 4 * CAPQ + NREG * 4 + NREG + WMAX + 2 * NREG;
    long   rem_f  = (long)(ws_size / 4) - (long)used_f;
    int W = (int)(rem_f / (6 * 64));
    if (W > WMAX) W = WMAX;
    if (W < 1024) W = 1024;
    W &= ~3;
    int B = W / 4;

    k_prehist<<<NCH, 256, 0, stream>>>(verts, faces, attrs, fb, hist);
    k_scan<<<1, 1024, 0, stream>>>(hist, len);
    k_scatterre<<<NCH, 256, 0, stream>>>(fb, hist, fb2);
    k_bin<<<NREG, 256, 0, stream>>>(fb2, rlist, cnt16, len);
    k_map<<<1, 256, 0, stream>>>(len, map, starts, Sarr, W);
    k_main<<<B, 256, 0, stream>>>(fb2, rlist, cnt16, map, Sarr, part);
    k_reduce<<<NREG, 256, 0, stream>>>(part, starts, Sarr, out);
}

// Round 14
// 148.893 us; speedup vs baseline: 1.1674x; 1.1674x over previous
//
#include <hip/hip_runtime.h>
#include <math.h>

// SoftRasterizer: B=1, V=5023, F=10000, IMG=128.
// R14 = R12 (139us, k_main 77) with:
//  - k_main: 4 independent waves per block each covering an 8x8 QUADRANT of
//    the 16x16 tile (square footprint -> fewer evals, earlier per-wave break)
//    while keeping R12's cheap tile-level lists (R13's per-region bin bloat
//    regressed total 139->174).
//  - 2-way unrolled list walk: both entries' tmeta + record-head scalar
//    chains issued up front (k_main was latency-bound, VALUBusy 52%).
//    Break checks stay in exact order -> bit-exact.
//  - k_map launch removed: map is a pure function of cnt4[256]; k_main and
//    k_reduce blocks re-derive it in LDS.
// Eval arithmetic bit-identical to R6-R12 (absmax 0.0078 <= 0.02).

#define NFACE 10000
#define IMG   128
#define P_TOT (IMG*IMG)
#define FSTR  40
#define NTILE 64               // 8x8 tiles of 16x16 px
#define NQ    4
#define CAPQ  2500             // quarter size (hard bound)
#define CAP   (CAPQ*NQ)
#define BMAX  4096
#define NB    1024             // z buckets
#define CH    256
#define NCH   40               // NFACE/CH
#define Z_LO  0.85f
#define Z_W   (0.12f/1024.0f)

__device__ __forceinline__ float rcp_nr(float x) {
    float r = __builtin_amdgcn_rcpf(x);
    r = r * __builtin_fmaf(-x, r, 2.0f);
    return r;
}

__device__ __forceinline__ float segd(float px, float py, float ax, float ay,
                                      float bx, float by, float il) {
    float dx = px - ax, dy = py - ay;
    float ex = bx - ax, ey = by - ay;
    float t = (dx * ex + dy * ey) * il;
    t = fminf(fmaxf(t, 0.0f), 1.0f);
    float rx = dx - t * ex, ry = dy - t * ey;
    return rx * rx + ry * ry;
}

__device__ __forceinline__ float rfl_f(float x) {
    return __uint_as_float(__builtin_amdgcn_readfirstlane(__float_as_uint(x)));
}

__device__ __forceinline__ int zbucket(float zub) {
    int b = (int)((zub - Z_LO) * (1.0f / Z_W));
    return min(max(b, 0), NB - 1);
}

// fused k_pre + k_hist
__global__ __launch_bounds__(256) void k_prehist(const float* __restrict__ v,
                                                 const int* __restrict__ fc,
                                                 const float* __restrict__ at,
                                                 float* __restrict__ fb,
                                                 int* __restrict__ hist) {
    __shared__ int lh[NB];
    int c = blockIdx.x, tid = threadIdx.x;
    for (int j = tid; j < NB; j += 256) lh[j] = 0;
    __syncthreads();

    int f = c * CH + tid;
    if (f < NFACE) {
        int i0 = fc[3 * f], i1 = fc[3 * f + 1], i2 = fc[3 * f + 2];
        float x0 = -v[3 * i0], y0 = v[3 * i0 + 1], z0 = v[3 * i0 + 2];
        float x1 = -v[3 * i1], y1 = v[3 * i1 + 1], z1 = v[3 * i1 + 2];
        float x2 = -v[3 * i2], y2 = v[3 * i2 + 1], z2 = v[3 * i2 + 2];

        float det = (y1 - y2) * (x0 - x2) + (x2 - x1) * (y0 - y2);
        if (fabsf(det) < 1e-10f) det = (det < 0.0f) ? -1e-10f : 1e-10f;
        float a0 = y1 - y2, b0 = x2 - x1, a1 = y2 - y0, b1 = x0 - x2, detp = det;
        if (det < 0.0f) { detp = -det; a0 = -a0; b0 = -b0; a1 = -a1; b1 = -b1; }

        float a2 = a0 + a1, b2 = b0 + b1;
        float g0 = fmaxf(sqrtf(a0 * a0 + b0 * b0), 1e-12f);
        float g1 = fmaxf(sqrtf(a1 * a1 + b1 * b1), 1e-12f);
        float g2 = fmaxf(sqrtf(a2 * a2 + b2 * b2), 1e-12f);
        const float MARG = 3e-5f, AG = 1e-9f;
        float m0 = -(MARG * g0 + AG), m1 = -(MARG * g1 + AG), m2 = -(MARG * g2 + AG);

        float e01x = x1 - x0, e01y = y1 - y0;
        float e12x = x2 - x1, e12y = y2 - y1;
        float e20x = x0 - x2, e20y = y0 - y2;
        float il01 = 1.0f / fmaxf(e01x * e01x + e01y * e01y, 1e-12f);
        float il12 = 1.0f / fmaxf(e12x * e12x + e12y * e12y, 1e-12f);
        float il20 = 1.0f / fmaxf(e20x * e20x + e20y * e20y, 1e-12f);

        const float BM = 2e-5f;
        float bxmin = fminf(fminf(x0, x1), x2) - BM, bxmax = fmaxf(fmaxf(x0, x1), x2) + BM;
        float bymin = fminf(fminf(y0, y1), y2) - BM, bymax = fmaxf(fmaxf(y0, y1), y2) + BM;

        int mult = (((y2 - y0) * (x1 - x0)) < ((y1 - y0) * (x2 - x0)))
                 + (((y0 - y2) * (x1 - x2)) < ((y1 - y2) * (x0 - x2)));

        float zmin = fminf(fminf(z0, z1), z2);
        float zub = (100.0f - zmin) / 99.0f + 2e-6f;

        float* F = fb + (size_t)f * FSTR;
        F[0] = bxmin; F[1] = bxmax; F[2] = bymin; F[3] = bymax;
        F[4] = x2; F[5] = y2; F[6] = a0; F[7] = b0;
        F[8] = a1; F[9] = b1; F[10] = detp; F[11] = zub;
        F[12] = m0; F[13] = m1; F[14] = m2; F[15] = (float)mult;
        F[16] = x0; F[17] = y0; F[18] = x1; F[19] = y1;
        F[20] = il01; F[21] = il12; F[22] = il20; F[23] = 1.0f / detp;
        F[24] = 1.0f / z0; F[25] = 1.0f / z1; F[26] = 1.0f / z2;
        F[27] = 1.0f / g0; F[28] = 1.0f / g1; F[29] = 1.0f / g2;
#pragma unroll
        for (int k = 0; k < 9; k++) F[30 + k] = at[(size_t)f * 9 + k];
        F[39] = 0.0f;

        atomicAdd(&lh[zbucket(zub)], 1);
    }
    __syncthreads();
    for (int j = tid; j < NB; j += 256) hist[c * NB + j] = lh[j];
}

// one block: suffix-sum over buckets (desc) + per-chunk bases in-place
__global__ __launch_bounds__(1024) void k_scan(int* __restrict__ hist) {
    __shared__ int a[NB];
    int t = threadIdx.x;
    int tot = 0;
    for (int c = 0; c < NCH; c++) tot += hist[c * NB + t];
    a[t] = tot;
    for (int off = 1; off < NB; off <<= 1) {
        __syncthreads();
        int v = a[t] + ((t + off < NB) ? a[t + off] : 0);
        __syncthreads();
        a[t] = v;
    }
    int r = a[t] - tot;
    for (int c = 0; c < NCH; c++) {
        int h = hist[c * NB + t];
        hist[c * NB + t] = r;
        r += h;
    }
}

// scatter + physical reorder: fb2[pos] = fb[f], F[11] := bucket upper bound
__global__ __launch_bounds__(256) void k_scatterre(const float* __restrict__ fb,
                                                   const int* __restrict__ hist,
                                                   float* __restrict__ fb2) {
    __shared__ int sb[CH];
    int c = blockIdx.x, tid = threadIdx.x;
    int f = c * CH + tid;
    bool valid = (f < NFACE);
    int b = valid ? zbucket(fb[(size_t)f * FSTR + 11]) : -1;
    sb[tid] = b;
    __syncthreads();
    if (valid) {
        int rank = 0;
        for (int j = 0; j < CH; j++) {
            int v2 = sb[j];
            rank += (j < tid && v2 == b) ? 1 : 0;
        }
        int pos = hist[c * NB + b] + rank;
        const float4* src = (const float4*)(fb + (size_t)f * FSTR);
        float4* dst = (float4*)(fb2 + (size_t)pos * FSTR);
#pragma unroll
        for (int k = 0; k < 10; k++) dst[k] = src[k];
        fb2[(size_t)pos * FSTR + 11] = Z_LO + (float)(b + 1) * Z_W + 1e-7f;
    }
}

// 256 blocks: (tile, quarter). Quarter q = z-desc rows [q*CAPQ,(q+1)*CAPQ).
__global__ __launch_bounds__(256) void k_bin(const float* __restrict__ fb2,
                                             float2* __restrict__ tmeta,
                                             int* __restrict__ cnt4) {
    int t = blockIdx.x >> 2, q = blockIdx.x & 3;
    int tid = threadIdx.x, wv = tid >> 6, lane = tid & 63;
    int tx = t & 7, ty = t >> 3;
    float x_lo = (float)(2 * (tx * 16) + 1 - IMG) / (float)IMG;
    float x_hi = (float)(2 * (tx * 16 + 15) + 1 - IMG) / (float)IMG;
    float y_hi = (float)(127 - 2 * (ty * 16)) / (float)IMG;
    float y_lo = (float)(127 - 2 * (ty * 16 + 15)) / (float)IMG;
    float cx = 0.5f * (x_lo + x_hi), hx = 0.5f * (x_hi - x_lo);
    float cy = 0.5f * (y_lo + y_hi), hy = 0.5f * (y_hi - y_lo);

    __shared__ int wc[4];
    int cnt = 0;
    int f0 = q * CAPQ;
    for (int base = f0; base < f0 + CAPQ; base += 256) {
        int j = base + tid;
        bool ov = false;
        float zub = 0.0f;
        if (j < f0 + CAPQ) {
            const float4* H = (const float4*)(fb2 + (size_t)j * FSTR);
            float4 h0 = H[0], h1 = H[1], h2 = H[2], h3 = H[3];
            ov = (h0.x <= x_hi) & (h0.y >= x_lo) & (h0.z <= y_hi) & (h0.w >= y_lo);
            if (ov) {
                float dx = cx - h1.x, dy = cy - h1.y;
                float mx0 = h1.z * dx + h1.w * dy + fabsf(h1.z) * hx + fabsf(h1.w) * hy;
                float mx1 = h2.x * dx + h2.y * dy + fabsf(h2.x) * hx + fabsf(h2.y) * hy;
                float A2 = -(h1.z + h2.x), B2 = -(h1.w + h2.y);
                float mx2 = h2.z + A2 * dx + B2 * dy + fabsf(A2) * hx + fabsf(B2) * hy;
                ov = (mx0 >= h3.x) & (mx1 >= h3.y) & (mx2 >= h3.z);
                zub = h2.w;
            }
        }
        unsigned long long mask = __ballot(ov);
        if (lane == 0) wc[wv] = __popcll(mask);
        __syncthreads();
        int off = cnt;
        for (int w = 0; w < 4; ++w) {
            if (w < wv) off += wc[w];
        }
        if (ov) {
            int pos = off + __popcll(mask & ((1ull << lane) - 1ull));
            tmeta[(size_t)t * CAP + q * CAPQ + pos] =
                make_float2(zub, __int_as_float(j));
        }
        cnt += wc[0] + wc[1] + wc[2] + wc[3];
        __syncthreads();
    }
    if (tid == 0) cnt4[t * 4 + q] = cnt;
}

// in-block map derivation (pure function of cnt4; replaces k_map kernel)
__device__ __forceinline__ void derive_map(const int* __restrict__ cnt4,
                                           int B, int tid, int nthr,
                                           int* sLen, int* sS, int* sP,
                                           int* sUsed) {
    if (tid < NTILE)
        sLen[tid] = cnt4[4 * tid] + cnt4[4 * tid + 1]
                  + cnt4[4 * tid + 2] + cnt4[4 * tid + 3];
    __syncthreads();
    if (tid == 0) {
        int tot = 0;
        for (int k = 0; k < NTILE; k++) tot += sLen[k];
        tot = max(tot, 1);
        int acc = 0;
        for (int k = 0; k < NTILE; k++) {
            int S = max(1, (int)(((long long)sLen[k] * (long long)(B - NTILE)) /
                                 (long long)tot));
            sS[k] = S; sP[k] = acc; acc += S;
        }
        *sUsed = acc;
    }
    __syncthreads();
}

// B blocks; block -> (tile,seg) via derived map; 4 independent waves, each
// covering an 8x8 quadrant; 2-way unrolled z-desc walk + absorbing break.
__global__ __launch_bounds__(256) void k_main(const float* __restrict__ fb2,
                                              const float2* __restrict__ tmeta,
                                              const int* __restrict__ cnt4,
                                              float* __restrict__ part,
                                              int B) {
    __shared__ int sLen[NTILE], sS[NTILE], sP[NTILE], sUsed;
    int tid = threadIdx.x;
    derive_map(cnt4, B, tid, 256, sLen, sS, sP, &sUsed);
    int bid = blockIdx.x;
    if (bid >= sUsed) return;
    // largest t with sP[t] <= bid (uniform across block)
    int lo = 0, hi = NTILE - 1;
    while (lo < hi) {
        int mid = (lo + hi + 1) >> 1;
        if (sP[mid] <= bid) lo = mid; else hi = mid - 1;
    }
    int t = lo, seg = bid - sP[lo];
    int S = sS[t];

    int wv = tid >> 6, lane = tid & 63;
    int tx = t & 7, ty = t >> 3;
    int col = tx * 16 + (wv & 1) * 8 + (lane & 7);
    int row = ty * 16 + (wv >> 1) * 8 + (lane >> 3);
    float px = (float)(2 * col + 1 - IMG) / (float)IMG;
    float py = (float)(2 * (IMG - 1 - row) + 1 - IMG) / (float)IMG;

    const float2* pm = tmeta + (size_t)t * CAP;

    float m = -__builtin_inff();
    float s = 0.0f, ca = 0.0f, cb = 0.0f, cc = 0.0f, pr = 1.0f;

    const float NEAR_T = 4.3e-3f;   // lb > this => sigmoid rounds to 1.0f exactly
    const float ZM = 1.3e-4f;       // exp((zpn-m)*1e6) == 0.0f beyond this gap

    auto EVAL = [&](int fj, float zcur, float4 g0, float4 g1, float4 g2, float4 g3) {
        bool inbox = (px >= g0.x) & (px <= g0.y) & (py >= g0.z) & (py <= g0.w);
        if (!__any(inbox)) return;

        float x2 = g1.x, y2 = g1.y;
        float dx2 = px - x2, dy2 = py - y2;
        float num0 = g1.z * dx2 + g1.w * dy2;
        float num1 = g2.x * dx2 + g2.y * dy2;
        float detp = g2.z;
        float num2 = detp - num0 - num1;
        bool maybe = inbox & (num0 >= g3.x) & (num1 >= g3.y) & (num2 >= g3.z);
        if (!__any(maybe)) return;

        const float* F = fb2 + (size_t)fj * FSTR;

        bool inside = (num0 >= 0.0f) & (num1 >= 0.0f) & (num2 >= 0.0f);
        bool inside_l = inside & inbox;

        float lin0 = num0 * F[27];
        float lin1 = num1 * F[28];
        float lin2 = num2 * F[29];
        float lbmin = fminf(fminf(lin0, lin1), lin2);

        bool outNear = maybe & (!inside);
        bool nearIn  = inside_l & (lbmin < NEAR_T);
        bool anyNear = __any(nearIn | outNear);

        float dis = 1e9f;
        float Dp;
        if (anyNear) {
            bool needAll = __any(outNear);
            float x0 = F[16], y0 = F[17], x1 = F[18], y1 = F[19];
            float d01 = 1e9f, d12 = 1e9f, d20 = 1e9f;
            if (needAll | __any(inside_l & (lin2 < NEAR_T)))
                d01 = segd(px, py, x0, y0, x1, y1, F[20]);
            if (needAll | __any(inside_l & (lin0 < NEAR_T)))
                d12 = segd(px, py, x1, y1, x2, y2, F[21]);
            if (needAll | __any(inside_l & (lin1 < NEAR_T)))
                d20 = segd(px, py, x2, y2, x0, y0, F[22]);
            dis = fminf(fminf(d01, d12), d20);

            float qq = dis * 1e6f;
            float xs_ = inside ? qq : -qq;
            float tt = __expf(-fabsf(xs_));
            float Dpn = (xs_ >= 0.0f ? 1.0f : tt) * rcp_nr(1.0f + tt);
            bool nearl = nearIn | outNear;
            Dp = nearl ? Dpn : (inside_l ? 1.0f : 0.0f);
        } else {
            Dp = inside_l ? 1.0f : 0.0f;
        }

        bool contrib = inside_l | (outNear & (dis < 1e-10f));
        Dp = contrib ? Dp : 0.0f;
        float omd = 1.0f - Dp;
        pr *= contrib ? (omd * omd) : 1.0f;   // both winding copies

        float multf = g3.w;
        bool doz = contrib & (multf > 0.0f);
        if (__any(doz & (zcur > m - ZM))) {
            float rdetp = F[23];
            float w0 = num0 * rdetp;
            float w1 = num1 * rdetp;
            float c0 = fminf(fmaxf(w0, 0.0f), 1.0f);
            float c1 = fminf(fmaxf(w1, 0.0f), 1.0f);
            float c2 = fminf(fmaxf(1.0f - w0 - w1, 0.0f), 1.0f);
            float csum = fmaxf(c0 + c1 + c2, 1e-5f);
            float rcs = rcp_nr(csum);
            c0 *= rcs; c1 *= rcs; c2 *= rcs;
            float zpi = c0 * F[24] + c1 * F[25] + c2 * F[26];
            if (fabsf(zpi) < 1e-12f) zpi = 1e-12f;
            float zp = rcp_nr(zpi);
            if (doz & (zp >= 1.0f) & (zp <= 100.0f)) {
                float zpn = (100.0f - zp) / 99.0f;   // keep IEEE: critical
                if (zpn > m) {
                    float scl = __expf((m - zpn) * 1e6f);
                    s *= scl; ca *= scl; cb *= scl; cc *= scl;
                    m = zpn;
                }
                float arg = (zpn - m) * 1e6f;
                if (arg > -110.0f) {
                    float e = __expf(arg) * Dp * multf;
                    float col0 = c0 * F[30] + c1 * F[33] + c2 * F[36];
                    float col1 = c0 * F[31] + c1 * F[34] + c2 * F[37];
                    float col2 = c0 * F[32] + c1 * F[35] + c2 * F[38];
                    s += e; ca += e * col0; cb += e * col1; cc += e * col2;
                }
            }
        }
    };

    bool done = false;
    for (int q = 0; q < 4 && !done; ++q) {
        int qlen = cnt4[t * 4 + q];
        const float2* pq = pm + q * CAPQ;
        int i = seg;
        while (i < qlen) {
            // issue both entries' meta + record heads up front (2x MLP)
            float2 mt0 = pq[i];
            int i1 = i + S;
            bool has1 = (i1 < qlen);
            float2 mt1 = has1 ? pq[i1] : mt0;
            float z0 = rfl_f(mt0.x);
            int   f0 = __builtin_amdgcn_readfirstlane(__float_as_int(mt0.y));
            float z1 = rfl_f(mt1.x);
            int   f1 = __builtin_amdgcn_readfirstlane(__float_as_int(mt1.y));
            const float4* H0 = (const float4*)(fb2 + (size_t)f0 * FSTR);
            const float4* H1 = (const float4*)(fb2 + (size_t)f1 * FSTR);
            float4 a0 = H0[0], a1 = H0[1], a2 = H0[2], a3 = H0[3];
            float4 b0 = H1[0], b1 = H1[1], b2 = H1[2], b3 = H1[3];

            if (__all((pr == 0.0f) & (z0 <= m - ZM))) { done = true; break; }
            EVAL(f0, z0, a0, a1, a2, a3);
            if (has1) {
                if (__all((pr == 0.0f) & (z1 <= m - ZM))) { done = true; break; }
                EVAL(f1, z1, b0, b1, b2, b3);
            }
            i += 2 * S;
        }
    }

    size_t pb = ((size_t)(bid * 4 + wv) * 6) * 64;
    part[pb + 0 * 64 + lane] = m;
    part[pb + 1 * 64 + lane] = s;
    part[pb + 2 * 64 + lane] = ca;
    part[pb + 3 * 64 + lane] = cb;
    part[pb + 4 * 64 + lane] = cc;
    part[pb + 5 * 64 + lane] = pr;
}

// 64 blocks x 1024 threads: pid=tid&255 (quadrant qd=pid>>6, lane=pid&63),
// sub=tid>>8; guarded exact online-softmax 4->1 LDS merge.
__global__ __launch_bounds__(1024) void k_reduce(const float* __restrict__ part,
                                                 const int* __restrict__ cnt4,
                                                 float* __restrict__ out,
                                                 int B) {
    __shared__ int sLen[NTILE], sS[NTILE], sP[NTILE], sUsed;
    __shared__ float sm[4][256], ss[4][256], sa[4][256], sb2[4][256],
                     sc[4][256], sp[4][256];
    int t = blockIdx.x;
    int tid = threadIdx.x;
    derive_map(cnt4, B, tid, 1024, sLen, sS, sP, &sUsed);
    int start = sP[t], S = sS[t];

    int pid = tid & 255, sub = tid >> 8;
    int qd = pid >> 6, lane = pid & 63;

    const float NINF = -__builtin_inff();
    float mp = NINF;
    for (int sgi = sub; sgi < S; sgi += 4)
        mp = fmaxf(mp, part[(((size_t)(start + sgi) * 4 + qd) * 6 + 0) * 64 + lane]);
    float sum = 0.0f, a = 0.0f, b = 0.0f, c = 0.0f, pr = 1.0f;
    for (int sgi = sub; sgi < S; sgi += 4) {
        const float* rp = part + (((size_t)(start + sgi) * 4 + qd) * 6) * 64;
        float rm = rp[0 * 64 + lane];
        float w = (rm == NINF) ? 0.0f : __expf((rm - mp) * 1e6f);
        pr *= rp[5 * 64 + lane];
        if (__any(w != 0.0f)) {
            sum += rp[1 * 64 + lane] * w;
            a += rp[2 * 64 + lane] * w;
            b += rp[3 * 64 + lane] * w;
            c += rp[4 * 64 + lane] * w;
        }
    }
    sm[sub][pid] = mp; ss[sub][pid] = sum; sa[sub][pid] = a;
    sb2[sub][pid] = b; sc[sub][pid] = c;  sp[sub][pid] = pr;
    __syncthreads();
    if (sub == 0) {
        int tx = t & 7, ty = t >> 3;
        int col = tx * 16 + (qd & 1) * 8 + (lane & 7);
        int row = ty * 16 + (qd >> 1) * 8 + (lane >> 3);
        int p = row * IMG + col;
        float M = 0.001f;   // BG_EPS
#pragma unroll
        for (int k = 0; k < 4; k++) M = fmaxf(M, sm[k][pid]);
        float SUM = __expf((0.001f - M) * 1e6f);   // background (s0=1); M finite
        float A = 0.0f, B2 = 0.0f, C = 0.0f, PR = 1.0f;
#pragma unroll
        for (int k = 0; k < 4; k++) {
            float w = __expf((sm[k][pid] - M) * 1e6f);   // sm=-inf -> 0
            SUM += ss[k][pid] * w;
            A += sa[k][pid] * w;
            B2 += sb2[k][pid] * w;
            C += sc[k][pid] * w;
            PR *= sp[k][pid];
        }
        out[0 * P_TOT + p] = A / SUM;
        out[1 * P_TOT + p] = B2 / SUM;
        out[2 * P_TOT + p] = C / SUM;
        out[3 * P_TOT + p] = 1.0f - PR;
    }
}

extern "C" void kernel_launch(void* const* d_in, const int* in_sizes, int n_in,
                              void* d_out, int out_size, void* d_ws, size_t ws_size,
                              hipStream_t stream) {
    const float* verts = (const float*)d_in[0];
    const int*   faces = (const int*)d_in[1];
    const float* attrs = (const float*)d_in[2];
    float* out = (float*)d_out;
    float* ws  = (float*)d_ws;

    float*  fb    = ws;                                    // 400k floats
    int*    hist  = (int*)(fb + (size_t)NFACE * FSTR);     // NCH*NB
    float*  fb2   = (float*)(hist + NCH * NB);             // 400k floats
    float2* tmeta = (float2*)(fb2 + (size_t)NFACE * FSTR); // NTILE*CAP float2
    int*    cnt4  = (int*)(tmeta + (size_t)NTILE * CAP);   // 256
    float*  part  = (float*)(cnt4 + NTILE * 4);

    size_t used_f = 2 * (size_t)NFACE * FSTR + NCH * NB
                  + 2 * (size_t)NTILE * CAP + NTILE * 4;
    long   rem_f  = (long)(ws_size / 4) - (long)used_f;
    int B = (int)(rem_f / (6 * 256));    // per block: 4 waves x 6 x 64 floats
    if (B > BMAX) B = BMAX;
    if (B < 256)  B = 256;

    k_prehist<<<NCH, 256, 0, stream>>>(verts, faces, attrs, fb, hist);
    k_scan<<<1, 1024, 0, stream>>>(hist);
    k_scatterre<<<NCH, 256, 0, stream>>>(fb, hist, fb2);
    k_bin<<<NTILE * NQ, 256, 0, stream>>>(fb2, tmeta, cnt4);
    k_main<<<B, 256, 0, stream>>>(fb2, tmeta, cnt4, part, B);
    k_reduce<<<NTILE, 1024, 0, stream>>>(part, cnt4, out, B);
}